// Round 6
// baseline (288.427 us; speedup 1.0000x reference)
//
#include <hip/hip_runtime.h>
#include <hip/hip_bf16.h>
#include <stdint.h>

#define DM   1024
#define NH   16
#define DH   64
#define TSEQ 2048
#define BATCH 4
#define NROW 8192      // B*T
#define NQKV 3072

typedef __attribute__((ext_vector_type(8)))  __bf16 bf16x8;
typedef __attribute__((ext_vector_type(4)))  float  f32x4;
typedef __attribute__((ext_vector_type(16))) float  f32x16;

static __device__ __forceinline__ void gload_lds16(const __bf16* g, __bf16* l) {
  __builtin_amdgcn_global_load_lds((const __attribute__((address_space(1))) void*)g,
                                   (__attribute__((address_space(3))) void*)l, 16, 0, 0);
}
static __device__ __forceinline__ float exp2a(float x) {
  float r; asm("v_exp_f32 %0, %1" : "=v"(r) : "v"(x)); return r;
}
static __device__ __forceinline__ uint32_t cvtpk(float a, float b) {
  uint32_t r; asm("v_cvt_pk_bf16_f32 %0, %1, %2" : "=v"(r) : "v"(a), "v"(b)); return r;
}

// ---------------- fp32 -> bf16 convert: x, w_qkv, w_proj in ONE launch ----------------
__global__ __launch_bounds__(256) void cvt_all(const float* __restrict__ x,
                                               const float* __restrict__ wq,
                                               const float* __restrict__ wp,
                                               __bf16* __restrict__ xb,
                                               __bf16* __restrict__ wqb,
                                               __bf16* __restrict__ wpb) {
  const int n8x = NROW * DM / 8, n8q = NQKV * DM / 8, n8p = DM * DM / 8;
  const int total = n8x + n8q + n8p;
  int i = blockIdx.x * blockDim.x + threadIdx.x;
  int stride = gridDim.x * blockDim.x;
  for (; i < total; i += stride) {
    const float* src; __bf16* dst; int k;
    if (i < n8x) { src = x; dst = xb; k = i; }
    else if (i < n8x + n8q) { src = wq; dst = wqb; k = i - n8x; }
    else { src = wp; dst = wpb; k = i - n8x - n8q; }
    const float4* p = (const float4*)(src + (size_t)k * 8);
    float4 a = p[0], b = p[1];
    bf16x8 o;
    o[0] = (__bf16)a.x; o[1] = (__bf16)a.y; o[2] = (__bf16)a.z; o[3] = (__bf16)a.w;
    o[4] = (__bf16)b.x; o[5] = (__bf16)b.y; o[6] = (__bf16)b.z; o[7] = (__bf16)b.w;
    *(bf16x8*)(dst + (size_t)k * 8) = o;
  }
}

// ---------------- bf16 GEMM, C = A[M,K] * B[N,K]^T (m97 structure) ----------------
// bm0 = block-row offset so a big GEMM can be split into multiple launches (profiling visibility).
template <int OUTF32>
__global__ __launch_bounds__(256) void gemm_bt(const __bf16* __restrict__ A,
                                               const __bf16* __restrict__ B,
                                               void* __restrict__ C,
                                               int M, int N, int K, int bm0) {
  __shared__ __bf16 As[128 * 64];
  __shared__ __bf16 Bs[128 * 64];
  const int nbn = N >> 7;
  const int bm = bm0 + blockIdx.x / nbn, bn = blockIdx.x % nbn;
  const int tid = threadIdx.x;
  const int lane = tid & 63, wid = tid >> 6;
  const int wr = wid >> 1, wc = wid & 1;

  f32x4 acc[4][4];
#pragma unroll
  for (int i = 0; i < 4; i++)
#pragma unroll
    for (int j = 0; j < 4; j++) acc[i][j] = (f32x4){0.f, 0.f, 0.f, 0.f};

  const __bf16* Abase = A + (size_t)(bm * 128) * K;
  const __bf16* Bbase = B + (size_t)(bn * 128) * K;

  for (int k0 = 0; k0 < K; k0 += 64) {
    __syncthreads();
#pragma unroll
    for (int it = 0; it < 4; ++it) {
      int e = it * 256 + tid;
      int row = e >> 3, c = (e & 7) * 8;
      gload_lds16(Abase + (size_t)row * K + k0 + c, As + e * 8);
      gload_lds16(Bbase + (size_t)row * K + k0 + c, Bs + e * 8);
    }
    __syncthreads();
#pragma unroll
    for (int kk = 0; kk < 2; ++kk) {
      const int kb = kk * 32 + (lane >> 4) * 8;
      bf16x8 af[4], bfr[4];
#pragma unroll
      for (int i = 0; i < 4; i++)
        af[i] = *(const bf16x8*)&As[(wr * 64 + i * 16 + (lane & 15)) * 64 + kb];
#pragma unroll
      for (int j = 0; j < 4; j++)
        bfr[j] = *(const bf16x8*)&Bs[(wc * 64 + j * 16 + (lane & 15)) * 64 + kb];
#pragma unroll
      for (int i = 0; i < 4; i++)
#pragma unroll
        for (int j = 0; j < 4; j++)
          acc[i][j] = __builtin_amdgcn_mfma_f32_16x16x32_bf16(af[i], bfr[j], acc[i][j], 0, 0, 0);
    }
  }

  const int crow0 = bm * 128 + wr * 64, ccol0 = bn * 128 + wc * 64;
#pragma unroll
  for (int i = 0; i < 4; i++)
#pragma unroll
    for (int j = 0; j < 4; j++) {
      int col = ccol0 + j * 16 + (lane & 15);
#pragma unroll
      for (int r = 0; r < 4; r++) {
        int row = crow0 + i * 16 + (lane >> 4) * 4 + r;
        if (OUTF32)
          ((float*)C)[(size_t)row * N + col] = acc[i][j][r];
        else
          ((__bf16*)C)[(size_t)row * N + col] = (__bf16)acc[i][j][r];
      }
    }
}

// ---------------- V transpose: qkv V-part [b][t][h*64+d] -> vt [b][h][d][t] ----------------
__global__ __launch_bounds__(256) void vtrans(const __bf16* __restrict__ qkv,
                                              __bf16* __restrict__ vt) {
  int tt = blockIdx.x & 31;
  int h = (blockIdx.x >> 5) & 15;
  int b = blockIdx.x >> 9;
  __shared__ __bf16 tile[64 * 64];  // [t][d]
  int tid = threadIdx.x;
  int trow = tid >> 2, c16 = (tid & 3) * 16;
#pragma unroll
  for (int u = 0; u < 2; ++u)
    *(bf16x8*)&tile[trow * 64 + c16 + u * 8] =
        *(const bf16x8*)(qkv + (size_t)(b * TSEQ + tt * 64 + trow) * NQKV + 2 * DM + h * DH + c16 + u * 8);
  __syncthreads();
  int drow = tid >> 2, t16 = (tid & 3) * 16;
  bf16x8 o0, o1;
#pragma unroll
  for (int u = 0; u < 8; u++) o0[u] = tile[(t16 + u) * 64 + drow];
#pragma unroll
  for (int u = 0; u < 8; u++) o1[u] = tile[(t16 + 8 + u) * 64 + drow];
  __bf16* dst = vt + ((size_t)((b * NH + h) * DH) + drow) * TSEQ + tt * 64 + t16;
  *(bf16x8*)dst = o0;
  *(bf16x8*)(dst + 8) = o1;
}

// ---------------- causal flash attention, swapped-QK^T 32x32 in-register softmax ----------------
// KV tile = 128 (half the barriers/drains of the 64-tile version). 4 waves x 32 q-rows = 128 q/block.
// S^T = mfma(K, Q): lane holds S[q=lane&31][kv=crow(r,hi)]. Softmax in-register (T12), defer-max (T13).
// A-frag fine structure is interleaved (k = 8*(e>>2) + 4*hi + (e&3)): QK^T C/D output IS the PV
// A-operand after pairwise bf16 packing; V B-frag read as two 8-byte chunks {4hi..+3},{8+4hi..+3}.
__global__ __launch_bounds__(256, 4) void attn2(const __bf16* __restrict__ qkv,
                                                const __bf16* __restrict__ vt,
                                                __bf16* __restrict__ y) {
  const int bid = blockIdx.x;
  const int qt = 15 - (bid >> 6);          // heavy-first
  const int bh = bid & 63;
  const int b = bh >> 4, h = bh & 15;
  const int tid = threadIdx.x, lane = tid & 63, w = tid >> 6;
  const int lq = lane & 31, hi = lane >> 5;
  const int qb0 = qt * 128 + w * 32;
  const float C2 = 0.125f * 1.44269504f;   // scale * log2(e); logits in log2 domain

  __shared__ __bf16 Ks[128 * 64];  // [s][d],  rows 128B, XOR-swizzled
  __shared__ __bf16 Vs[64 * 128];  // [d][s],  rows 256B, XOR-swizzled

  const __bf16* qp = qkv + (size_t)(b * TSEQ + qb0 + lq) * NQKV + h * DH;
  bf16x8 qf[4];
#pragma unroll
  for (int ks = 0; ks < 4; ks++) qf[ks] = *(const bf16x8*)(qp + ks * 16 + hi * 8);

  f32x16 o0 = {}, o1 = {};           // O d-halves; row=crow(r,hi)=q, col=lq=d
  float m = -1e30f, lsum = 0.f;

  const __bf16* kg = qkv + (size_t)b * TSEQ * NQKV + DM + h * DH;
  const __bf16* vg = vt + (size_t)((b * NH + h) * DH) * TSEQ;

  const int nkv = qt + 1;            // 128-wide kv tiles
  for (int t0 = 0; t0 < nkv; ++t0) {
    const int s0 = t0 * 128;
    __syncthreads();
#pragma unroll
    for (int it = 0; it < 4; ++it) {  // K: 128 rows x 64 (8 slots/row)
      int e = it * 256 + tid;
      int row = e >> 3, slot = e & 7;
      int gc = (slot ^ (row & 7)) * 8;
      gload_lds16(kg + (size_t)(s0 + row) * NQKV + gc, Ks + e * 8);
    }
#pragma unroll
    for (int it = 0; it < 4; ++it) {  // V: 64 rows x 128 (16 slots/row)
      int e = it * 256 + tid;
      int row = e >> 4, slot = e & 15;
      int gc = (slot ^ (row & 7)) * 8;
      gload_lds16(vg + (size_t)row * TSEQ + s0 + gc, Vs + e * 8);
    }
    __syncthreads();

#pragma unroll
    for (int g = 0; g < 4; ++g) {
      const int s0g = s0 + g * 32;
      if (s0g <= qb0 + 31) {
        // ---- S^T = K·Q^T over D=64 (4 k-steps) ----
        f32x16 sacc = {};
        __builtin_amdgcn_s_setprio(1);
#pragma unroll
        for (int ks = 0; ks < 4; ks++) {
          int row = g * 32 + lq;
          int cb = (ks * 32 + hi * 16) ^ ((row & 7) << 4);
          bf16x8 kf = *(const bf16x8*)((const char*)Ks + row * 128 + cb);
          sacc = __builtin_amdgcn_mfma_f32_32x32x16_bf16(kf, qf[ks], sacc, 0, 0, 0);
        }
        __builtin_amdgcn_s_setprio(0);
        // ---- scale + causal mask (reg r -> kv = s0g + (r&3)+8*(r>>2)+4*hi, q=lq) ----
        const int qg = qb0 + lq;
        const int kvb = s0g + (hi << 2);
        if (s0g + 31 > qb0) {
#pragma unroll
          for (int r = 0; r < 16; r++) {
            const int off = (r & 3) + 8 * (r >> 2);
            sacc[r] = (kvb + off > qg) ? -3.0e38f : sacc[r] * C2;
          }
        } else {
#pragma unroll
          for (int r = 0; r < 16; r++) sacc[r] *= C2;
        }
        // ---- row max: in-reg tree + pair exchange ----
        float pm = -3.0e38f;
#pragma unroll
        for (int r = 0; r < 16; r++) pm = fmaxf(pm, sacc[r]);
        pm = fmaxf(pm, __shfl_xor(pm, 32));
        // ---- defer-max (T13): rescale only if some row grew > 8 (log2) ----
        if (__any(pm > m + 8.0f)) {
          float mn = fmaxf(m, pm);
          float al = exp2a(m - mn);
          m = mn;
          lsum *= al;
#pragma unroll
          for (int r = 0; r < 16; r++) {
            const int off = (r & 3) + 8 * (r >> 2);
            float ar = __shfl(al, off + (hi << 2), 64);
            o0[r] *= ar; o1[r] *= ar;
          }
        }
        // ---- P = exp2(S - m); A-frag element e == sacc reg e (identity) ----
        union { uint32_t u[4]; bf16x8 v; } pa0, pa1;
        {
          float pe[16];
#pragma unroll
          for (int r = 0; r < 16; r++) { pe[r] = exp2a(sacc[r] - m); lsum += pe[r]; }
#pragma unroll
          for (int i = 0; i < 4; i++) pa0.u[i] = cvtpk(pe[2 * i], pe[2 * i + 1]);
#pragma unroll
          for (int i = 0; i < 4; i++) pa1.u[i] = cvtpk(pe[8 + 2 * i], pe[9 + 2 * i]);
        }
        // ---- O += P·V; V B-frag: two 8B chunks per 16-kv step ----
        __builtin_amdgcn_s_setprio(1);
#pragma unroll
        for (int ks2 = 0; ks2 < 2; ks2++) {
          const bf16x8 pa = ks2 ? pa1.v : pa0.v;
#pragma unroll
          for (int dh = 0; dh < 2; dh++) {
            int row = dh * 32 + lq;
            int sw = (row & 7) << 4;
            int b0 = g * 64 + ks2 * 32 + hi * 8;
            const char* base = (const char*)Vs + row * 256;
            union { uint32_t u[4]; bf16x8 v; } vf;
            *(uint2*)&vf.u[0] = *(const uint2*)(base + (b0 ^ sw));
            *(uint2*)&vf.u[2] = *(const uint2*)(base + ((b0 + 16) ^ sw));
            if (dh == 0) o0 = __builtin_amdgcn_mfma_f32_32x32x16_bf16(pa, vf.v, o0, 0, 0, 0);
            else         o1 = __builtin_amdgcn_mfma_f32_32x32x16_bf16(pa, vf.v, o1, 0, 0, 0);
          }
        }
        __builtin_amdgcn_s_setprio(0);
      }
    }
  }

  // ---- finalize: L = pair-sum, broadcast 1/L, store ----
  float Lf = lsum + __shfl_xor(lsum, 32);
  float inv = 1.0f / Lf;
#pragma unroll
  for (int r = 0; r < 16; r++) {
    const int off = (r & 3) + 8 * (r >> 2);
    float ivr = __shfl(inv, off + (hi << 2), 64);
    int qrow = qb0 + off + (hi << 2);
    __bf16* yp = y + (size_t)(b * TSEQ + qrow) * DM + h * DH;
    yp[lq] = (__bf16)(o0[r] * ivr);
    yp[32 + lq] = (__bf16)(o1[r] * ivr);
  }
}

// ---------------- launcher ----------------
extern "C" void kernel_launch(void* const* d_in, const int* in_sizes, int n_in,
                              void* d_out, int out_size, void* d_ws, size_t ws_size,
                              hipStream_t stream) {
  const float* x = (const float*)d_in[0];
  const float* w_qkv = (const float*)d_in[1];
  const float* w_proj = (const float*)d_in[2];
  float* out = (float*)d_out;

  char* ws = (char*)d_ws;
  __bf16* xb   = (__bf16*)(ws);
  __bf16* wqb  = (__bf16*)(ws + 16777216);
  __bf16* wpb  = (__bf16*)(ws + 23068672);
  __bf16* qkvb = (__bf16*)(ws + 25165824);
  __bf16* vtb  = (__bf16*)(ws + 75497472);
  __bf16* yb   = (__bf16*)(ws + 92274688);

  cvt_all<<<1024, 256, 0, stream>>>(x, w_qkv, w_proj, xb, wqb, wpb);

  // QKV GEMM split into two half-grids (profiling visibility; same total work)
  gemm_bt<0><<<(NROW / 256) * (NQKV / 128), 256, 0, stream>>>(xb, wqb, qkvb, NROW, NQKV, DM, 0);
  gemm_bt<0><<<(NROW / 256) * (NQKV / 128), 256, 0, stream>>>(xb, wqb, qkvb, NROW, NQKV, DM, NROW / 256);

  vtrans<<<BATCH * NH * (TSEQ / 64), 256, 0, stream>>>(qkvb, vtb);
  attn2<<<BATCH * NH * (TSEQ / 128), 256, 0, stream>>>(qkvb, vtb, yb);
  gemm_bt<1><<<(NROW / 128) * (DM / 128), 256, 0, stream>>>(yb, wpb, out, NROW, DM, DM, 0);
}

// Round 7
// 276.845 us; speedup vs baseline: 1.0418x; 1.0418x over previous
//
#include <hip/hip_runtime.h>
#include <hip/hip_bf16.h>
#include <stdint.h>

#define DM   1024
#define NH   16
#define DH   64
#define TSEQ 2048
#define BATCH 4
#define NROW 8192      // B*T
#define NQKV 3072

typedef __attribute__((ext_vector_type(8)))  __bf16 bf16x8;
typedef __attribute__((ext_vector_type(4)))  float  f32x4;
typedef __attribute__((ext_vector_type(16))) float  f32x16;

static __device__ __forceinline__ void gload_lds16(const __bf16* g, __bf16* l) {
  __builtin_amdgcn_global_load_lds((const __attribute__((address_space(1))) void*)g,
                                   (__attribute__((address_space(3))) void*)l, 16, 0, 0);
}
static __device__ __forceinline__ float exp2a(float x) {
  float r; asm("v_exp_f32 %0, %1" : "=v"(r) : "v"(x)); return r;
}
static __device__ __forceinline__ uint32_t cvtpk(float a, float b) {
  uint32_t r; asm("v_cvt_pk_bf16_f32 %0, %1, %2" : "=v"(r) : "v"(a), "v"(b)); return r;
}

// ---------------- fp32 -> bf16 convert: x, w_qkv (Q-rows pre-scaled), w_proj ----------------
// Q-rows of w_qkv get 0.125*log2(e) folded in: Q only feeds QK^T, whose logits we
// consume in the log2 domain — removes the per-element scale pass in attention.
__global__ __launch_bounds__(256) void cvt_all(const float* __restrict__ x,
                                               const float* __restrict__ wq,
                                               const float* __restrict__ wp,
                                               __bf16* __restrict__ xb,
                                               __bf16* __restrict__ wqb,
                                               __bf16* __restrict__ wpb) {
  const int n8x = NROW * DM / 8, n8q = NQKV * DM / 8, n8p = DM * DM / 8;
  const int total = n8x + n8q + n8p;
  int i = blockIdx.x * blockDim.x + threadIdx.x;
  int stride = gridDim.x * blockDim.x;
  for (; i < total; i += stride) {
    const float* src; __bf16* dst; int k;
    float sc = 1.0f;
    if (i < n8x) { src = x; dst = xb; k = i; }
    else if (i < n8x + n8q) {
      src = wq; dst = wqb; k = i - n8x;
      if (k < n8q / 3) sc = 0.125f * 1.44269504f;  // Q out-features
    } else { src = wp; dst = wpb; k = i - n8x - n8q; }
    const float4* p = (const float4*)(src + (size_t)k * 8);
    float4 a = p[0], b = p[1];
    bf16x8 o;
    o[0] = (__bf16)(a.x * sc); o[1] = (__bf16)(a.y * sc);
    o[2] = (__bf16)(a.z * sc); o[3] = (__bf16)(a.w * sc);
    o[4] = (__bf16)(b.x * sc); o[5] = (__bf16)(b.y * sc);
    o[6] = (__bf16)(b.z * sc); o[7] = (__bf16)(b.w * sc);
    *(bf16x8*)(dst + (size_t)k * 8) = o;
  }
}

// ---------------- bf16 GEMM, C = A[M,K] * B[N,K]^T (m97 structure) ----------------
template <int OUTF32>
__global__ __launch_bounds__(256) void gemm_bt(const __bf16* __restrict__ A,
                                               const __bf16* __restrict__ B,
                                               void* __restrict__ C,
                                               int M, int N, int K, int bm0) {
  __shared__ __bf16 As[128 * 64];
  __shared__ __bf16 Bs[128 * 64];
  const int nbn = N >> 7;
  const int bm = bm0 + blockIdx.x / nbn, bn = blockIdx.x % nbn;
  const int tid = threadIdx.x;
  const int lane = tid & 63, wid = tid >> 6;
  const int wr = wid >> 1, wc = wid & 1;

  f32x4 acc[4][4];
#pragma unroll
  for (int i = 0; i < 4; i++)
#pragma unroll
    for (int j = 0; j < 4; j++) acc[i][j] = (f32x4){0.f, 0.f, 0.f, 0.f};

  const __bf16* Abase = A + (size_t)(bm * 128) * K;
  const __bf16* Bbase = B + (size_t)(bn * 128) * K;

  for (int k0 = 0; k0 < K; k0 += 64) {
    __syncthreads();
#pragma unroll
    for (int it = 0; it < 4; ++it) {
      int e = it * 256 + tid;
      int row = e >> 3, c = (e & 7) * 8;
      gload_lds16(Abase + (size_t)row * K + k0 + c, As + e * 8);
      gload_lds16(Bbase + (size_t)row * K + k0 + c, Bs + e * 8);
    }
    __syncthreads();
#pragma unroll
    for (int kk = 0; kk < 2; ++kk) {
      const int kb = kk * 32 + (lane >> 4) * 8;
      bf16x8 af[4], bfr[4];
#pragma unroll
      for (int i = 0; i < 4; i++)
        af[i] = *(const bf16x8*)&As[(wr * 64 + i * 16 + (lane & 15)) * 64 + kb];
#pragma unroll
      for (int j = 0; j < 4; j++)
        bfr[j] = *(const bf16x8*)&Bs[(wc * 64 + j * 16 + (lane & 15)) * 64 + kb];
#pragma unroll
      for (int i = 0; i < 4; i++)
#pragma unroll
        for (int j = 0; j < 4; j++)
          acc[i][j] = __builtin_amdgcn_mfma_f32_16x16x32_bf16(af[i], bfr[j], acc[i][j], 0, 0, 0);
    }
  }

  const int crow0 = bm * 128 + wr * 64, ccol0 = bn * 128 + wc * 64;
#pragma unroll
  for (int i = 0; i < 4; i++)
#pragma unroll
    for (int j = 0; j < 4; j++) {
      int col = ccol0 + j * 16 + (lane & 15);
#pragma unroll
      for (int r = 0; r < 4; r++) {
        int row = crow0 + i * 16 + (lane >> 4) * 4 + r;
        if (OUTF32)
          ((float*)C)[(size_t)row * N + col] = acc[i][j][r];
        else
          ((__bf16*)C)[(size_t)row * N + col] = (__bf16)acc[i][j][r];
      }
    }
}

// ---------------- V transpose: qkv V-part [b][t][h*64+d] -> vt [b][h][d][t] ----------------
__global__ __launch_bounds__(256) void vtrans(const __bf16* __restrict__ qkv,
                                              __bf16* __restrict__ vt) {
  int tt = blockIdx.x & 31;
  int h = (blockIdx.x >> 5) & 15;
  int b = blockIdx.x >> 9;
  __shared__ __bf16 tile[64 * 64];  // [t][d]
  int tid = threadIdx.x;
  int trow = tid >> 2, c16 = (tid & 3) * 16;
#pragma unroll
  for (int u = 0; u < 2; ++u)
    *(bf16x8*)&tile[trow * 64 + c16 + u * 8] =
        *(const bf16x8*)(qkv + (size_t)(b * TSEQ + tt * 64 + trow) * NQKV + 2 * DM + h * DH + c16 + u * 8);
  __syncthreads();
  int drow = tid >> 2, t16 = (tid & 3) * 16;
  bf16x8 o0, o1;
#pragma unroll
  for (int u = 0; u < 8; u++) o0[u] = tile[(t16 + u) * 64 + drow];
#pragma unroll
  for (int u = 0; u < 8; u++) o1[u] = tile[(t16 + 8 + u) * 64 + drow];
  __bf16* dst = vt + ((size_t)((b * NH + h) * DH) + drow) * TSEQ + tt * 64 + t16;
  *(bf16x8*)dst = o0;
  *(bf16x8*)(dst + 8) = o1;
}

// ---------------- causal flash attention, qt-paired for load balance ----------------
// 512 blocks: pair p = bid>>6 processes q-tiles {15-p, p} sequentially -> every block
// exactly 17 kv-tile units of work. 4 waves x 32 q-rows; KV tile 128; in-register
// softmax (T12), defer-max (T13), setprio (T5). Q pre-scaled (log2 domain).
__global__ __launch_bounds__(256, 4) void attn3(const __bf16* __restrict__ qkv,
                                                const __bf16* __restrict__ vt,
                                                __bf16* __restrict__ y) {
  const int bid = blockIdx.x;
  const int pr = bid >> 6;
  const int bh = bid & 63;
  const int b = bh >> 4, h = bh & 15;
  const int tid = threadIdx.x, lane = tid & 63, w = tid >> 6;
  const int lq = lane & 31, hi = lane >> 5;

  __shared__ __bf16 Ks[128 * 64];  // [s][d],  rows 128B, XOR-swizzled
  __shared__ __bf16 Vs[64 * 128];  // [d][s],  rows 256B, XOR-swizzled

  const __bf16* kg = qkv + (size_t)b * TSEQ * NQKV + DM + h * DH;
  const __bf16* vg = vt + (size_t)((b * NH + h) * DH) * TSEQ;

  for (int pass = 0; pass < 2; ++pass) {
    const int qt = pass ? pr : 15 - pr;
    const int qb0 = qt * 128 + w * 32;

    const __bf16* qp = qkv + (size_t)(b * TSEQ + qb0 + lq) * NQKV + h * DH;
    bf16x8 qf[4];
#pragma unroll
    for (int ks = 0; ks < 4; ks++) qf[ks] = *(const bf16x8*)(qp + ks * 16 + hi * 8);

    f32x16 o0 = {}, o1 = {};          // O d-halves; row=crow(r,hi)=q, col=lq=d
    float m = -1e30f, lsum = 0.f;

    for (int t0 = 0; t0 <= qt; ++t0) {
      const int s0 = t0 * 128;
      __syncthreads();
#pragma unroll
      for (int it = 0; it < 4; ++it) {  // K: 128 rows x 64 (8 slots/row)
        int e = it * 256 + tid;
        int row = e >> 3, slot = e & 7;
        int gc = (slot ^ (row & 7)) * 8;
        gload_lds16(kg + (size_t)(s0 + row) * NQKV + gc, Ks + e * 8);
      }
#pragma unroll
      for (int it = 0; it < 4; ++it) {  // V: 64 rows x 128 (16 slots/row)
        int e = it * 256 + tid;
        int row = e >> 4, slot = e & 15;
        int gc = (slot ^ (row & 7)) * 8;
        gload_lds16(vg + (size_t)row * TSEQ + s0 + gc, Vs + e * 8);
      }
      __syncthreads();

#pragma unroll
      for (int g = 0; g < 4; ++g) {
        const int s0g = s0 + g * 32;
        if (s0g <= qb0 + 31) {
          // ---- S^T = K·Q^T over D=64 (4 k-steps); logits already in log2 domain ----
          f32x16 sacc = {};
          __builtin_amdgcn_s_setprio(1);
#pragma unroll
          for (int ks = 0; ks < 4; ks++) {
            int row = g * 32 + lq;
            int cb = (ks * 32 + hi * 16) ^ ((row & 7) << 4);
            bf16x8 kf = *(const bf16x8*)((const char*)Ks + row * 128 + cb);
            sacc = __builtin_amdgcn_mfma_f32_32x32x16_bf16(kf, qf[ks], sacc, 0, 0, 0);
          }
          __builtin_amdgcn_s_setprio(0);
          // ---- causal mask only on diagonal chunks (reg r -> kv = s0g+(r&3)+8*(r>>2)+4hi) ----
          const int qg = qb0 + lq;
          const int kvb = s0g + (hi << 2);
          if (s0g + 31 > qb0) {
#pragma unroll
            for (int r = 0; r < 16; r++) {
              const int off = (r & 3) + 8 * (r >> 2);
              if (kvb + off > qg) sacc[r] = -3.0e38f;
            }
          }
          // ---- row max: in-reg tree + pair exchange ----
          float pm = -3.0e38f;
#pragma unroll
          for (int r = 0; r < 16; r++) pm = fmaxf(pm, sacc[r]);
          pm = fmaxf(pm, __shfl_xor(pm, 32));
          // ---- defer-max (T13): rescale only if some row grew > 8 (log2) ----
          if (__any(pm > m + 8.0f)) {
            float mn = fmaxf(m, pm);
            float al = exp2a(m - mn);
            m = mn;
            lsum *= al;
#pragma unroll
            for (int r = 0; r < 16; r++) {
              const int off = (r & 3) + 8 * (r >> 2);
              float ar = __shfl(al, off + (hi << 2), 64);
              o0[r] *= ar; o1[r] *= ar;
            }
          }
          // ---- P = exp2(S - m); A-frag element e == sacc reg e (identity) ----
          union { uint32_t u[4]; bf16x8 v; } pa0, pa1;
          {
            float pe[16];
#pragma unroll
            for (int r = 0; r < 16; r++) { pe[r] = exp2a(sacc[r] - m); lsum += pe[r]; }
#pragma unroll
            for (int i = 0; i < 4; i++) pa0.u[i] = cvtpk(pe[2 * i], pe[2 * i + 1]);
#pragma unroll
            for (int i = 0; i < 4; i++) pa1.u[i] = cvtpk(pe[8 + 2 * i], pe[9 + 2 * i]);
          }
          // ---- O += P·V; V B-frag: two 8B chunks per 16-kv step ----
          __builtin_amdgcn_s_setprio(1);
#pragma unroll
          for (int ks2 = 0; ks2 < 2; ks2++) {
            const bf16x8 pa = ks2 ? pa1.v : pa0.v;
#pragma unroll
            for (int dh = 0; dh < 2; dh++) {
              int row = dh * 32 + lq;
              int sw = (row & 7) << 4;
              int b0 = g * 64 + ks2 * 32 + hi * 8;
              const char* base = (const char*)Vs + row * 256;
              union { uint32_t u[4]; bf16x8 v; } vf;
              *(uint2*)&vf.u[0] = *(const uint2*)(base + (b0 ^ sw));
              *(uint2*)&vf.u[2] = *(const uint2*)(base + ((b0 + 16) ^ sw));
              if (dh == 0) o0 = __builtin_amdgcn_mfma_f32_32x32x16_bf16(pa, vf.v, o0, 0, 0, 0);
              else         o1 = __builtin_amdgcn_mfma_f32_32x32x16_bf16(pa, vf.v, o1, 0, 0, 0);
            }
          }
          __builtin_amdgcn_s_setprio(0);
        }
      }
    }

    // ---- finalize: L = pair-sum, broadcast 1/L, store ----
    float Lf = lsum + __shfl_xor(lsum, 32);
    float inv = 1.0f / Lf;
#pragma unroll
    for (int r = 0; r < 16; r++) {
      const int off = (r & 3) + 8 * (r >> 2);
      float ivr = __shfl(inv, off + (hi << 2), 64);
      int qrow = qb0 + off + (hi << 2);
      __bf16* yp = y + (size_t)(b * TSEQ + qrow) * DM + h * DH;
      yp[lq] = (__bf16)(o0[r] * ivr);
      yp[32 + lq] = (__bf16)(o1[r] * ivr);
    }
  }
}

// ---------------- launcher ----------------
extern "C" void kernel_launch(void* const* d_in, const int* in_sizes, int n_in,
                              void* d_out, int out_size, void* d_ws, size_t ws_size,
                              hipStream_t stream) {
  const float* x = (const float*)d_in[0];
  const float* w_qkv = (const float*)d_in[1];
  const float* w_proj = (const float*)d_in[2];
  float* out = (float*)d_out;

  char* ws = (char*)d_ws;
  __bf16* xb   = (__bf16*)(ws);
  __bf16* wqb  = (__bf16*)(ws + 16777216);
  __bf16* wpb  = (__bf16*)(ws + 23068672);
  __bf16* qkvb = (__bf16*)(ws + 25165824);
  __bf16* vtb  = (__bf16*)(ws + 75497472);
  __bf16* yb   = (__bf16*)(ws + 92274688);

  cvt_all<<<1024, 256, 0, stream>>>(x, w_qkv, w_proj, xb, wqb, wpb);
  gemm_bt<0><<<(NROW / 128) * (NQKV / 128), 256, 0, stream>>>(xb, wqb, qkvb, NROW, NQKV, DM, 0);
  vtrans<<<BATCH * NH * (TSEQ / 64), 256, 0, stream>>>(qkvb, vtb);
  attn3<<<8 * 64, 256, 0, stream>>>(qkvb, vtb, yb);
  gemm_bt<1><<<(NROW / 128) * (DM / 128), 256, 0, stream>>>(yb, wpb, out, NROW, DM, DM, 0);
}

// Round 8
// 260.382 us; speedup vs baseline: 1.1077x; 1.0632x over previous
//
#include <hip/hip_runtime.h>
#include <hip/hip_bf16.h>
#include <stdint.h>

#define DM   1024
#define NH   16
#define DH   64
#define TSEQ 2048
#define BATCH 4
#define NROW 8192      // B*T
#define NQKV 3072

typedef __attribute__((ext_vector_type(8)))  __bf16 bf16x8;
typedef __attribute__((ext_vector_type(4)))  float  f32x4;
typedef __attribute__((ext_vector_type(16))) float  f32x16;

static __device__ __forceinline__ void gload_lds16(const __bf16* g, __bf16* l) {
  __builtin_amdgcn_global_load_lds((const __attribute__((address_space(1))) void*)g,
                                   (__attribute__((address_space(3))) void*)l, 16, 0, 0);
}
static __device__ __forceinline__ float exp2a(float x) {
  float r; asm("v_exp_f32 %0, %1" : "=v"(r) : "v"(x)); return r;
}
static __device__ __forceinline__ uint32_t cvtpk(float a, float b) {
  uint32_t r; asm("v_cvt_pk_bf16_f32 %0, %1, %2" : "=v"(r) : "v"(a), "v"(b)); return r;
}

// ---------------- fp32 -> bf16 convert: x, w_qkv (Q-rows pre-scaled), w_proj ----------------
__global__ __launch_bounds__(256) void cvt_all(const float* __restrict__ x,
                                               const float* __restrict__ wq,
                                               const float* __restrict__ wp,
                                               __bf16* __restrict__ xb,
                                               __bf16* __restrict__ wqb,
                                               __bf16* __restrict__ wpb) {
  const int n8x = NROW * DM / 8, n8q = NQKV * DM / 8, n8p = DM * DM / 8;
  const int total = n8x + n8q + n8p;
  int i = blockIdx.x * blockDim.x + threadIdx.x;
  int stride = gridDim.x * blockDim.x;
  for (; i < total; i += stride) {
    const float* src; __bf16* dst; int k;
    float sc = 1.0f;
    if (i < n8x) { src = x; dst = xb; k = i; }
    else if (i < n8x + n8q) {
      src = wq; dst = wqb; k = i - n8x;
      if (k < n8q / 3) sc = 0.125f * 1.44269504f;  // Q out-features -> log2 domain
    } else { src = wp; dst = wpb; k = i - n8x - n8q; }
    const float4* p = (const float4*)(src + (size_t)k * 8);
    float4 a = p[0], b = p[1];
    bf16x8 o;
    o[0] = (__bf16)(a.x * sc); o[1] = (__bf16)(a.y * sc);
    o[2] = (__bf16)(a.z * sc); o[3] = (__bf16)(a.w * sc);
    o[4] = (__bf16)(b.x * sc); o[5] = (__bf16)(b.y * sc);
    o[6] = (__bf16)(b.z * sc); o[7] = (__bf16)(b.w * sc);
    *(bf16x8*)(dst + (size_t)k * 8) = o;
  }
}

// ======== deep-pipeline 256x256 GEMM, C = A[M,K]*B[N,K]^T, bf16 out ========
// 512 thr / 8 waves (2M x 4N); BK=32; LDS = 4-slot ring x (A[256][32]+B[256][32]) = 128KB.
// Phase t: STAGE(t+3) -> vmcnt(counted, never 0 mid-loop) -> barrier -> swizzled ds_read
// -> lgkmcnt(0) -> barrier (seals reads before slot reuse) -> setprio(1) 32 MFMA setprio(0).
// Swizzle: involution l ^= ((l>>7)&7)<<4 (byte addr); staged via pre-swizzled global source.
__global__ __launch_bounds__(512, 2) void gemm256(const __bf16* __restrict__ A,
                                                  const __bf16* __restrict__ B,
                                                  __bf16* __restrict__ C,
                                                  int M, int N, int K) {
  extern __shared__ __bf16 ring[];  // [4][16384]: per slot A(8192 el) then B(8192 el)
  const int nbn = N >> 8;
  const int bm = blockIdx.x / nbn, bn = blockIdx.x % nbn;
  const int tid = threadIdx.x, lane = tid & 63;
  const int wid = tid >> 6, wr = wid >> 2, wc = wid & 3;
  const int nk = K >> 5;

  f32x4 acc[8][4];
#pragma unroll
  for (int m = 0; m < 8; m++)
#pragma unroll
    for (int n = 0; n < 4; n++) acc[m][n] = (f32x4){0.f, 0.f, 0.f, 0.f};

  const __bf16* Ab = A + (size_t)(bm * 256) * K;
  const __bf16* Bb = B + (size_t)(bn * 256) * K;

#define G256_STAGE(kt)                                                          \
  {                                                                             \
    const int slot_ = (kt) & 3;                                                 \
    __bf16* sA_ = ring + slot_ * 16384;                                         \
    const int k0_ = (kt) * 32;                                                  \
    _Pragma("unroll")                                                           \
    for (int it_ = 0; it_ < 2; ++it_) {                                         \
      int e_ = it_ * 512 + tid;                                                 \
      int row_ = e_ >> 2, ch_ = e_ & 3;                                         \
      int srow_ = row_ ^ ((row_ >> 3) & 1);                                     \
      int scol_ = (ch_ ^ ((row_ >> 1) & 3)) * 8;                                \
      gload_lds16(Ab + (size_t)srow_ * K + k0_ + scol_, sA_ + e_ * 8);          \
      gload_lds16(Bb + (size_t)srow_ * K + k0_ + scol_, sA_ + 8192 + e_ * 8);   \
    }                                                                           \
  }

  G256_STAGE(0)
  G256_STAGE(1)
  G256_STAGE(2)

  for (int t = 0; t < nk; ++t) {
    if (t + 3 < nk) G256_STAGE(t + 3)
    // counted wait: tile t's 4 loads were issued 3 phases ago
    if (t < nk - 3)       asm volatile("s_waitcnt vmcnt(12)" ::: "memory");
    else if (t == nk - 3) asm volatile("s_waitcnt vmcnt(8)"  ::: "memory");
    else if (t == nk - 2) asm volatile("s_waitcnt vmcnt(4)"  ::: "memory");
    else                  asm volatile("s_waitcnt vmcnt(0)"  ::: "memory");
    __builtin_amdgcn_s_barrier();  // ring[t&3] fully staged for all waves

    const __bf16* sA = ring + (t & 3) * 16384;
    const __bf16* sB = sA + 8192;
    const int cb = (lane >> 4) * 16;  // K-chunk byte offset
    bf16x8 af[8], bfr[4];
#pragma unroll
    for (int m = 0; m < 8; m++) {
      int row = wr * 128 + m * 16 + (lane & 15);
      int l = row * 64 + cb;
      af[m] = *(const bf16x8*)((const char*)sA + (l ^ (((l >> 7) & 7) << 4)));
    }
#pragma unroll
    for (int n = 0; n < 4; n++) {
      int row = wc * 64 + n * 16 + (lane & 15);
      int l = row * 64 + cb;
      bfr[n] = *(const bf16x8*)((const char*)sB + (l ^ (((l >> 7) & 7) << 4)));
    }
    asm volatile("s_waitcnt lgkmcnt(0)" ::: "memory");
    __builtin_amdgcn_s_barrier();  // all reads of ring[t&3] done -> next STAGE safe

    __builtin_amdgcn_s_setprio(1);
#pragma unroll
    for (int m = 0; m < 8; m++)
#pragma unroll
      for (int n = 0; n < 4; n++)
        acc[m][n] = __builtin_amdgcn_mfma_f32_16x16x32_bf16(af[m], bfr[n], acc[m][n], 0, 0, 0);
    __builtin_amdgcn_s_setprio(0);
  }

  const int crow0 = bm * 256 + wr * 128, ccol0 = bn * 256 + wc * 64;
#pragma unroll
  for (int m = 0; m < 8; m++)
#pragma unroll
    for (int n = 0; n < 4; n++) {
      int col = ccol0 + n * 16 + (lane & 15);
#pragma unroll
      for (int r = 0; r < 4; r++) {
        int row = crow0 + m * 16 + (lane >> 4) * 4 + r;
        C[(size_t)row * N + col] = (__bf16)acc[m][n][r];
      }
    }
}

// ---------------- bf16 GEMM, 128^2 m97 structure (kept for gemm2) ----------------
template <int OUTF32>
__global__ __launch_bounds__(256) void gemm_bt(const __bf16* __restrict__ A,
                                               const __bf16* __restrict__ B,
                                               void* __restrict__ C,
                                               int M, int N, int K, int bm0) {
  __shared__ __bf16 As[128 * 64];
  __shared__ __bf16 Bs[128 * 64];
  const int nbn = N >> 7;
  const int bm = bm0 + blockIdx.x / nbn, bn = blockIdx.x % nbn;
  const int tid = threadIdx.x;
  const int lane = tid & 63, wid = tid >> 6;
  const int wr = wid >> 1, wc = wid & 1;

  f32x4 acc[4][4];
#pragma unroll
  for (int i = 0; i < 4; i++)
#pragma unroll
    for (int j = 0; j < 4; j++) acc[i][j] = (f32x4){0.f, 0.f, 0.f, 0.f};

  const __bf16* Abase = A + (size_t)(bm * 128) * K;
  const __bf16* Bbase = B + (size_t)(bn * 128) * K;

  for (int k0 = 0; k0 < K; k0 += 64) {
    __syncthreads();
#pragma unroll
    for (int it = 0; it < 4; ++it) {
      int e = it * 256 + tid;
      int row = e >> 3, c = (e & 7) * 8;
      gload_lds16(Abase + (size_t)row * K + k0 + c, As + e * 8);
      gload_lds16(Bbase + (size_t)row * K + k0 + c, Bs + e * 8);
    }
    __syncthreads();
#pragma unroll
    for (int kk = 0; kk < 2; ++kk) {
      const int kb = kk * 32 + (lane >> 4) * 8;
      bf16x8 af[4], bfr[4];
#pragma unroll
      for (int i = 0; i < 4; i++)
        af[i] = *(const bf16x8*)&As[(wr * 64 + i * 16 + (lane & 15)) * 64 + kb];
#pragma unroll
      for (int j = 0; j < 4; j++)
        bfr[j] = *(const bf16x8*)&Bs[(wc * 64 + j * 16 + (lane & 15)) * 64 + kb];
#pragma unroll
      for (int i = 0; i < 4; i++)
#pragma unroll
        for (int j = 0; j < 4; j++)
          acc[i][j] = __builtin_amdgcn_mfma_f32_16x16x32_bf16(af[i], bfr[j], acc[i][j], 0, 0, 0);
    }
  }

  const int crow0 = bm * 128 + wr * 64, ccol0 = bn * 128 + wc * 64;
#pragma unroll
  for (int i = 0; i < 4; i++)
#pragma unroll
    for (int j = 0; j < 4; j++) {
      int col = ccol0 + j * 16 + (lane & 15);
#pragma unroll
      for (int r = 0; r < 4; r++) {
        int row = crow0 + i * 16 + (lane >> 4) * 4 + r;
        if (OUTF32)
          ((float*)C)[(size_t)row * N + col] = acc[i][j][r];
        else
          ((__bf16*)C)[(size_t)row * N + col] = (__bf16)acc[i][j][r];
      }
    }
}

// ---------------- V transpose: qkv V-part [b][t][h*64+d] -> vt [b][h][d][t] ----------------
__global__ __launch_bounds__(256) void vtrans(const __bf16* __restrict__ qkv,
                                              __bf16* __restrict__ vt) {
  int tt = blockIdx.x & 31;
  int h = (blockIdx.x >> 5) & 15;
  int b = blockIdx.x >> 9;
  __shared__ __bf16 tile[64 * 64];  // [t][d]
  int tid = threadIdx.x;
  int trow = tid >> 2, c16 = (tid & 3) * 16;
#pragma unroll
  for (int u = 0; u < 2; ++u)
    *(bf16x8*)&tile[trow * 64 + c16 + u * 8] =
        *(const bf16x8*)(qkv + (size_t)(b * TSEQ + tt * 64 + trow) * NQKV + 2 * DM + h * DH + c16 + u * 8);
  __syncthreads();
  int drow = tid >> 2, t16 = (tid & 3) * 16;
  bf16x8 o0, o1;
#pragma unroll
  for (int u = 0; u < 8; u++) o0[u] = tile[(t16 + u) * 64 + drow];
#pragma unroll
  for (int u = 0; u < 8; u++) o1[u] = tile[(t16 + 8 + u) * 64 + drow];
  __bf16* dst = vt + ((size_t)((b * NH + h) * DH) + drow) * TSEQ + tt * 64 + t16;
  *(bf16x8*)dst = o0;
  *(bf16x8*)(dst + 8) = o1;
}

// ---------------- causal flash attention (R6 measured config + Q-prescale) ----------------
// grid 1024: qt = 15-(bid>>6) heavy-first; 4 waves x 32 q-rows; KV tile 128.
__global__ __launch_bounds__(256, 4) void attn4(const __bf16* __restrict__ qkv,
                                                const __bf16* __restrict__ vt,
                                                __bf16* __restrict__ y) {
  const int bid = blockIdx.x;
  const int qt = 15 - (bid >> 6);
  const int bh = bid & 63;
  const int b = bh >> 4, h = bh & 15;
  const int tid = threadIdx.x, lane = tid & 63, w = tid >> 6;
  const int lq = lane & 31, hi = lane >> 5;
  const int qb0 = qt * 128 + w * 32;

  __shared__ __bf16 Ks[128 * 64];  // [s][d], XOR-swizzled
  __shared__ __bf16 Vs[64 * 128];  // [d][s], XOR-swizzled

  const __bf16* qp = qkv + (size_t)(b * TSEQ + qb0 + lq) * NQKV + h * DH;
  bf16x8 qf[4];
#pragma unroll
  for (int ks = 0; ks < 4; ks++) qf[ks] = *(const bf16x8*)(qp + ks * 16 + hi * 8);

  f32x16 o0 = {}, o1 = {};
  float m = -1e30f, lsum = 0.f;

  const __bf16* kg = qkv + (size_t)b * TSEQ * NQKV + DM + h * DH;
  const __bf16* vg = vt + (size_t)((b * NH + h) * DH) * TSEQ;

  const int nkv = qt + 1;
  for (int t0 = 0; t0 < nkv; ++t0) {
    const int s0 = t0 * 128;
    __syncthreads();
#pragma unroll
    for (int it = 0; it < 4; ++it) {  // K: 128 rows x 64
      int e = it * 256 + tid;
      int row = e >> 3, slot = e & 7;
      int gc = (slot ^ (row & 7)) * 8;
      gload_lds16(kg + (size_t)(s0 + row) * NQKV + gc, Ks + e * 8);
    }
#pragma unroll
    for (int it = 0; it < 4; ++it) {  // V: 64 rows x 128
      int e = it * 256 + tid;
      int row = e >> 4, slot = e & 15;
      int gc = (slot ^ (row & 7)) * 8;
      gload_lds16(vg + (size_t)row * TSEQ + s0 + gc, Vs + e * 8);
    }
    __syncthreads();

#pragma unroll
    for (int g = 0; g < 4; ++g) {
      const int s0g = s0 + g * 32;
      if (s0g <= qb0 + 31) {
        f32x16 sacc = {};
        __builtin_amdgcn_s_setprio(1);
#pragma unroll
        for (int ks = 0; ks < 4; ks++) {
          int row = g * 32 + lq;
          int cbk = (ks * 32 + hi * 16) ^ ((row & 7) << 4);
          bf16x8 kf = *(const bf16x8*)((const char*)Ks + row * 128 + cbk);
          sacc = __builtin_amdgcn_mfma_f32_32x32x16_bf16(kf, qf[ks], sacc, 0, 0, 0);
        }
        __builtin_amdgcn_s_setprio(0);
        const int qg = qb0 + lq;
        const int kvb = s0g + (hi << 2);
        if (s0g + 31 > qb0) {
#pragma unroll
          for (int r = 0; r < 16; r++) {
            const int off = (r & 3) + 8 * (r >> 2);
            if (kvb + off > qg) sacc[r] = -3.0e38f;
          }
        }
        float pm = -3.0e38f;
#pragma unroll
        for (int r = 0; r < 16; r++) pm = fmaxf(pm, sacc[r]);
        pm = fmaxf(pm, __shfl_xor(pm, 32));
        if (__any(pm > m + 8.0f)) {
          float mn = fmaxf(m, pm);
          float al = exp2a(m - mn);
          m = mn;
          lsum *= al;
#pragma unroll
          for (int r = 0; r < 16; r++) {
            const int off = (r & 3) + 8 * (r >> 2);
            float ar = __shfl(al, off + (hi << 2), 64);
            o0[r] *= ar; o1[r] *= ar;
          }
        }
        union { uint32_t u[4]; bf16x8 v; } pa0, pa1;
        {
          float pe[16];
#pragma unroll
          for (int r = 0; r < 16; r++) { pe[r] = exp2a(sacc[r] - m); lsum += pe[r]; }
#pragma unroll
          for (int i = 0; i < 4; i++) pa0.u[i] = cvtpk(pe[2 * i], pe[2 * i + 1]);
#pragma unroll
          for (int i = 0; i < 4; i++) pa1.u[i] = cvtpk(pe[8 + 2 * i], pe[9 + 2 * i]);
        }
        __builtin_amdgcn_s_setprio(1);
#pragma unroll
        for (int ks2 = 0; ks2 < 2; ks2++) {
          const bf16x8 pa = ks2 ? pa1.v : pa0.v;
#pragma unroll
          for (int dh = 0; dh < 2; dh++) {
            int row = dh * 32 + lq;
            int sw = (row & 7) << 4;
            int b0 = g * 64 + ks2 * 32 + hi * 8;
            const char* base = (const char*)Vs + row * 256;
            union { uint32_t u[4]; bf16x8 v; } vf;
            *(uint2*)&vf.u[0] = *(const uint2*)(base + (b0 ^ sw));
            *(uint2*)&vf.u[2] = *(const uint2*)(base + ((b0 + 16) ^ sw));
            if (dh == 0) o0 = __builtin_amdgcn_mfma_f32_32x32x16_bf16(pa, vf.v, o0, 0, 0, 0);
            else         o1 = __builtin_amdgcn_mfma_f32_32x32x16_bf16(pa, vf.v, o1, 0, 0, 0);
          }
        }
        __builtin_amdgcn_s_setprio(0);
      }
    }
  }

  float Lf = lsum + __shfl_xor(lsum, 32);
  float inv = 1.0f / Lf;
#pragma unroll
  for (int r = 0; r < 16; r++) {
    const int off = (r & 3) + 8 * (r >> 2);
    float ivr = __shfl(inv, off + (hi << 2), 64);
    int qrow = qb0 + off + (hi << 2);
    __bf16* yp = y + (size_t)(b * TSEQ + qrow) * DM + h * DH;
    yp[lq] = (__bf16)(o0[r] * ivr);
    yp[32 + lq] = (__bf16)(o1[r] * ivr);
  }
}

// ---------------- launcher ----------------
extern "C" void kernel_launch(void* const* d_in, const int* in_sizes, int n_in,
                              void* d_out, int out_size, void* d_ws, size_t ws_size,
                              hipStream_t stream) {
  const float* x = (const float*)d_in[0];
  const float* w_qkv = (const float*)d_in[1];
  const float* w_proj = (const float*)d_in[2];
  float* out = (float*)d_out;

  char* ws = (char*)d_ws;
  __bf16* xb   = (__bf16*)(ws);
  __bf16* wqb  = (__bf16*)(ws + 16777216);
  __bf16* wpb  = (__bf16*)(ws + 23068672);
  __bf16* qkvb = (__bf16*)(ws + 25165824);
  __bf16* vtb  = (__bf16*)(ws + 75497472);
  __bf16* yb   = (__bf16*)(ws + 92274688);

  // allow 128KB dynamic LDS for gemm256 (idempotent; safe under graph capture)
  hipFuncSetAttribute((const void*)gemm256, hipFuncAttributeMaxDynamicSharedMemorySize, 131072);

  cvt_all<<<1024, 256, 0, stream>>>(x, w_qkv, w_proj, xb, wqb, wpb);
  gemm256<<<(NROW / 256) * (NQKV / 256), 512, 131072, stream>>>(xb, wqb, qkvb, NROW, NQKV, DM);
  vtrans<<<BATCH * NH * (TSEQ / 64), 256, 0, stream>>>(qkvb, vtb);
  attn4<<<BATCH * NH * (TSEQ / 128), 256, 0, stream>>>(qkvb, vtb, yb);
  gemm_bt<1><<<(NROW / 128) * (DM / 128), 256, 0, stream>>>(yb, wpb, out, NROW, DM, DM, 0);
}

// Round 9
// 247.384 us; speedup vs baseline: 1.1659x; 1.0525x over previous
//
#include <hip/hip_runtime.h>
#include <hip/hip_bf16.h>
#include <stdint.h>

#define DM   1024
#define NH   16
#define DH   64
#define TSEQ 2048
#define BATCH 4
#define NROW 8192      // B*T
#define NQKV 3072

typedef __attribute__((ext_vector_type(8)))  __bf16 bf16x8;
typedef __attribute__((ext_vector_type(4)))  float  f32x4;
typedef __attribute__((ext_vector_type(16))) float  f32x16;

static __device__ __forceinline__ void gload_lds16(const __bf16* g, __bf16* l) {
  __builtin_amdgcn_global_load_lds((const __attribute__((address_space(1))) void*)g,
                                   (__attribute__((address_space(3))) void*)l, 16, 0, 0);
}
static __device__ __forceinline__ float exp2a(float x) {
  float r; asm("v_exp_f32 %0, %1" : "=v"(r) : "v"(x)); return r;
}
static __device__ __forceinline__ uint32_t cvtpk(float a, float b) {
  uint32_t r; asm("v_cvt_pk_bf16_f32 %0, %1, %2" : "=v"(r) : "v"(a), "v"(b)); return r;
}

// ---------------- fp32 -> bf16 convert: x, w_qkv (Q-rows pre-scaled), w_proj ----------------
__global__ __launch_bounds__(256) void cvt_all(const float* __restrict__ x,
                                               const float* __restrict__ wq,
                                               const float* __restrict__ wp,
                                               __bf16* __restrict__ xb,
                                               __bf16* __restrict__ wqb,
                                               __bf16* __restrict__ wpb) {
  const int n8x = NROW * DM / 8, n8q = NQKV * DM / 8, n8p = DM * DM / 8;
  const int total = n8x + n8q + n8p;
  int i = blockIdx.x * blockDim.x + threadIdx.x;
  int stride = gridDim.x * blockDim.x;
  for (; i < total; i += stride) {
    const float* src; __bf16* dst; int k;
    float sc = 1.0f;
    if (i < n8x) { src = x; dst = xb; k = i; }
    else if (i < n8x + n8q) {
      src = wq; dst = wqb; k = i - n8x;
      if (k < n8q / 3) sc = 0.125f * 1.44269504f;  // Q out-features -> log2 domain
    } else { src = wp; dst = wpb; k = i - n8x - n8q; }
    const float4* p = (const float4*)(src + (size_t)k * 8);
    float4 a = p[0], b = p[1];
    bf16x8 o;
    o[0] = (__bf16)(a.x * sc); o[1] = (__bf16)(a.y * sc);
    o[2] = (__bf16)(a.z * sc); o[3] = (__bf16)(a.w * sc);
    o[4] = (__bf16)(b.x * sc); o[5] = (__bf16)(b.y * sc);
    o[6] = (__bf16)(b.z * sc); o[7] = (__bf16)(b.w * sc);
    *(bf16x8*)(dst + (size_t)k * 8) = o;
  }
}

// ======== deep-pipeline 128x256 GEMM, C = A[M,K]*B[N,K]^T ========
// 256 thr / 4 waves (1M x 4N); BK=32; 3-slot LDS ring x (A[128][32]+B[256][32]) = 72KB
// -> 2 blocks/CU co-resident; grid (M/128)x(N/256) balanced on 256 CUs.
// Phase t: STAGE(t+2) -> counted vmcnt -> barrier(slot staged) -> swizzled ds_read
// -> lgkmcnt(0)+sched_barrier (per-wave! stagger preserved) -> 32 MFMA -> barrier(seal).
// Swizzle: read phys = l ^ (((l>>7)&7)<<4); stage source pre-swizzled (verified 0-conflict R8).
template <int OUTF32>
__global__ __launch_bounds__(256, 2) void gemmdp(const __bf16* __restrict__ A,
                                                 const __bf16* __restrict__ B,
                                                 void* __restrict__ C,
                                                 int M, int N, int K) {
  extern __shared__ __bf16 ring[];  // 3 slots x 12288 el (A 4096 + B 8192)
  const int nbn = N >> 8;
  const int nwg = gridDim.x;
  int bid = blockIdx.x;
  bid = (bid & 7) * (nwg >> 3) + (bid >> 3);  // XCD-aware swizzle (nwg % 8 == 0)
  const int bm = bid / nbn, bn = bid % nbn;
  const int tid = threadIdx.x, lane = tid & 63;
  const int wc = tid >> 6;
  const int nk = K >> 5;

  f32x4 acc[8][4];
#pragma unroll
  for (int m = 0; m < 8; m++)
#pragma unroll
    for (int n = 0; n < 4; n++) acc[m][n] = (f32x4){0.f, 0.f, 0.f, 0.f};

  const __bf16* Ab = A + (size_t)(bm * 128) * K;
  const __bf16* Bb = B + (size_t)(bn * 256) * K;

#define DP_STAGE(kt)                                                            \
  {                                                                             \
    __bf16* s_ = ring + ((kt) % 3) * 12288;                                     \
    const int k0_ = (kt) << 5;                                                  \
    _Pragma("unroll")                                                           \
    for (int it_ = 0; it_ < 2; ++it_) { /* A: 128 rows x 4 chunks */            \
      int c_ = it_ * 256 + tid;                                                 \
      int row_ = c_ >> 2, ch_ = c_ & 3;                                         \
      int srow_ = row_ ^ ((row_ >> 3) & 1);                                     \
      int scol_ = (ch_ ^ ((row_ >> 1) & 3)) * 8;                                \
      gload_lds16(Ab + (size_t)srow_ * K + k0_ + scol_, s_ + c_ * 8);           \
    }                                                                           \
    _Pragma("unroll")                                                           \
    for (int it_ = 0; it_ < 4; ++it_) { /* B: 256 rows x 4 chunks */            \
      int c_ = it_ * 256 + tid;                                                 \
      int row_ = c_ >> 2, ch_ = c_ & 3;                                         \
      int srow_ = row_ ^ ((row_ >> 3) & 1);                                     \
      int scol_ = (ch_ ^ ((row_ >> 1) & 3)) * 8;                                \
      gload_lds16(Bb + (size_t)srow_ * K + k0_ + scol_, s_ + 4096 + c_ * 8);    \
    }                                                                           \
  }

  DP_STAGE(0)
  DP_STAGE(1)

  for (int t = 0; t < nk; ++t) {
    if (t + 2 < nk) DP_STAGE(t + 2)
    // counted wait: slot t's 6 loads were issued 2 phases ago (6 loads/stage, depth 2)
    if (t < nk - 2)       asm volatile("s_waitcnt vmcnt(12)" ::: "memory");
    else if (t == nk - 2) asm volatile("s_waitcnt vmcnt(6)"  ::: "memory");
    else                  asm volatile("s_waitcnt vmcnt(0)"  ::: "memory");
    __builtin_amdgcn_s_barrier();  // all waves' loads for slot t done

    const __bf16* sA = ring + (t % 3) * 12288;
    const __bf16* sB = sA + 4096;
    const int cb = (lane >> 4) * 16;  // K-chunk byte offset
    bf16x8 af[8], bfr[4];
#pragma unroll
    for (int m = 0; m < 8; m++) {
      int l = (m * 16 + (lane & 15)) * 64 + cb;
      af[m] = *(const bf16x8*)((const char*)sA + (l ^ (((l >> 7) & 7) << 4)));
    }
#pragma unroll
    for (int n = 0; n < 4; n++) {
      int l = (wc * 64 + n * 16 + (lane & 15)) * 64 + cb;
      bfr[n] = *(const bf16x8*)((const char*)sB + (l ^ (((l >> 7) & 7) << 4)));
    }
    asm volatile("s_waitcnt lgkmcnt(0)" ::: "memory");  // per-wave: stagger preserved
    __builtin_amdgcn_sched_barrier(0);                  // rule 18: pin MFMA below the wait

    __builtin_amdgcn_s_setprio(1);
#pragma unroll
    for (int m = 0; m < 8; m++)
#pragma unroll
      for (int n = 0; n < 4; n++)
        acc[m][n] = __builtin_amdgcn_mfma_f32_16x16x32_bf16(af[m], bfr[n], acc[m][n], 0, 0, 0);
    __builtin_amdgcn_s_setprio(0);
    __builtin_amdgcn_s_barrier();  // seal: all reads of slot t done; next phase stages slot t
  }

  const int crow0 = bm * 128, ccol0 = bn * 256 + wc * 64;
#pragma unroll
  for (int m = 0; m < 8; m++)
#pragma unroll
    for (int n = 0; n < 4; n++) {
      int col = ccol0 + n * 16 + (lane & 15);
#pragma unroll
      for (int r = 0; r < 4; r++) {
        int row = crow0 + m * 16 + (lane >> 4) * 4 + r;
        if (OUTF32) ((float*)C)[(size_t)row * N + col] = acc[m][n][r];
        else        ((__bf16*)C)[(size_t)row * N + col] = (__bf16)acc[m][n][r];
      }
    }
}

// ---------------- V transpose: qkv V-part [b][t][h*64+d] -> vt [b][h][d][t] ----------------
__global__ __launch_bounds__(256) void vtrans(const __bf16* __restrict__ qkv,
                                              __bf16* __restrict__ vt) {
  int tt = blockIdx.x & 31;
  int h = (blockIdx.x >> 5) & 15;
  int b = blockIdx.x >> 9;
  __shared__ __bf16 tile[64 * 64];  // [t][d]
  int tid = threadIdx.x;
  int trow = tid >> 2, c16 = (tid & 3) * 16;
#pragma unroll
  for (int u = 0; u < 2; ++u)
    *(bf16x8*)&tile[trow * 64 + c16 + u * 8] =
        *(const bf16x8*)(qkv + (size_t)(b * TSEQ + tt * 64 + trow) * NQKV + 2 * DM + h * DH + c16 + u * 8);
  __syncthreads();
  int drow = tid >> 2, t16 = (tid & 3) * 16;
  bf16x8 o0, o1;
#pragma unroll
  for (int u = 0; u < 8; u++) o0[u] = tile[(t16 + u) * 64 + drow];
#pragma unroll
  for (int u = 0; u < 8; u++) o1[u] = tile[(t16 + 8 + u) * 64 + drow];
  __bf16* dst = vt + ((size_t)((b * NH + h) * DH) + drow) * TSEQ + tt * 64 + t16;
  *(bf16x8*)dst = o0;
  *(bf16x8*)(dst + 8) = o1;
}

// ---------------- causal flash attention (R8 measured config, unchanged) ----------------
__global__ __launch_bounds__(256, 4) void attn4(const __bf16* __restrict__ qkv,
                                                const __bf16* __restrict__ vt,
                                                __bf16* __restrict__ y) {
  const int bid = blockIdx.x;
  const int qt = 15 - (bid >> 6);
  const int bh = bid & 63;
  const int b = bh >> 4, h = bh & 15;
  const int tid = threadIdx.x, lane = tid & 63, w = tid >> 6;
  const int lq = lane & 31, hi = lane >> 5;
  const int qb0 = qt * 128 + w * 32;

  __shared__ __bf16 Ks[128 * 64];  // [s][d], XOR-swizzled
  __shared__ __bf16 Vs[64 * 128];  // [d][s], XOR-swizzled

  const __bf16* qp = qkv + (size_t)(b * TSEQ + qb0 + lq) * NQKV + h * DH;
  bf16x8 qf[4];
#pragma unroll
  for (int ks = 0; ks < 4; ks++) qf[ks] = *(const bf16x8*)(qp + ks * 16 + hi * 8);

  f32x16 o0 = {}, o1 = {};
  float m = -1e30f, lsum = 0.f;

  const __bf16* kg = qkv + (size_t)b * TSEQ * NQKV + DM + h * DH;
  const __bf16* vg = vt + (size_t)((b * NH + h) * DH) * TSEQ;

  const int nkv = qt + 1;
  for (int t0 = 0; t0 < nkv; ++t0) {
    const int s0 = t0 * 128;
    __syncthreads();
#pragma unroll
    for (int it = 0; it < 4; ++it) {  // K: 128 rows x 64
      int e = it * 256 + tid;
      int row = e >> 3, slot = e & 7;
      int gc = (slot ^ (row & 7)) * 8;
      gload_lds16(kg + (size_t)(s0 + row) * NQKV + gc, Ks + e * 8);
    }
#pragma unroll
    for (int it = 0; it < 4; ++it) {  // V: 64 rows x 128
      int e = it * 256 + tid;
      int row = e >> 4, slot = e & 15;
      int gc = (slot ^ (row & 7)) * 8;
      gload_lds16(vg + (size_t)row * TSEQ + s0 + gc, Vs + e * 8);
    }
    __syncthreads();

#pragma unroll
    for (int g = 0; g < 4; ++g) {
      const int s0g = s0 + g * 32;
      if (s0g <= qb0 + 31) {
        f32x16 sacc = {};
        __builtin_amdgcn_s_setprio(1);
#pragma unroll
        for (int ks = 0; ks < 4; ks++) {
          int row = g * 32 + lq;
          int cbk = (ks * 32 + hi * 16) ^ ((row & 7) << 4);
          bf16x8 kf = *(const bf16x8*)((const char*)Ks + row * 128 + cbk);
          sacc = __builtin_amdgcn_mfma_f32_32x32x16_bf16(kf, qf[ks], sacc, 0, 0, 0);
        }
        __builtin_amdgcn_s_setprio(0);
        const int qg = qb0 + lq;
        const int kvb = s0g + (hi << 2);
        if (s0g + 31 > qb0) {
#pragma unroll
          for (int r = 0; r < 16; r++) {
            const int off = (r & 3) + 8 * (r >> 2);
            if (kvb + off > qg) sacc[r] = -3.0e38f;
          }
        }
        float pm = -3.0e38f;
#pragma unroll
        for (int r = 0; r < 16; r++) pm = fmaxf(pm, sacc[r]);
        pm = fmaxf(pm, __shfl_xor(pm, 32));
        if (__any(pm > m + 8.0f)) {
          float mn = fmaxf(m, pm);
          float al = exp2a(m - mn);
          m = mn;
          lsum *= al;
#pragma unroll
          for (int r = 0; r < 16; r++) {
            const int off = (r & 3) + 8 * (r >> 2);
            float ar = __shfl(al, off + (hi << 2), 64);
            o0[r] *= ar; o1[r] *= ar;
          }
        }
        union { uint32_t u[4]; bf16x8 v; } pa0, pa1;
        {
          float pe[16];
#pragma unroll
          for (int r = 0; r < 16; r++) { pe[r] = exp2a(sacc[r] - m); lsum += pe[r]; }
#pragma unroll
          for (int i = 0; i < 4; i++) pa0.u[i] = cvtpk(pe[2 * i], pe[2 * i + 1]);
#pragma unroll
          for (int i = 0; i < 4; i++) pa1.u[i] = cvtpk(pe[8 + 2 * i], pe[9 + 2 * i]);
        }
        __builtin_amdgcn_s_setprio(1);
#pragma unroll
        for (int ks2 = 0; ks2 < 2; ks2++) {
          const bf16x8 pa = ks2 ? pa1.v : pa0.v;
#pragma unroll
          for (int dh = 0; dh < 2; dh++) {
            int row = dh * 32 + lq;
            int sw = (row & 7) << 4;
            int b0 = g * 64 + ks2 * 32 + hi * 8;
            const char* base = (const char*)Vs + row * 256;
            union { uint32_t u[4]; bf16x8 v; } vf;
            *(uint2*)&vf.u[0] = *(const uint2*)(base + (b0 ^ sw));
            *(uint2*)&vf.u[2] = *(const uint2*)(base + ((b0 + 16) ^ sw));
            if (dh == 0) o0 = __builtin_amdgcn_mfma_f32_32x32x16_bf16(pa, vf.v, o0, 0, 0, 0);
            else         o1 = __builtin_amdgcn_mfma_f32_32x32x16_bf16(pa, vf.v, o1, 0, 0, 0);
          }
        }
        __builtin_amdgcn_s_setprio(0);
      }
    }
  }

  float Lf = lsum + __shfl_xor(lsum, 32);
  float inv = 1.0f / Lf;
#pragma unroll
  for (int r = 0; r < 16; r++) {
    const int off = (r & 3) + 8 * (r >> 2);
    float ivr = __shfl(inv, off + (hi << 2), 64);
    int qrow = qb0 + off + (hi << 2);
    __bf16* yp = y + (size_t)(b * TSEQ + qrow) * DM + h * DH;
    yp[lq] = (__bf16)(o0[r] * ivr);
    yp[32 + lq] = (__bf16)(o1[r] * ivr);
  }
}

// ---------------- launcher ----------------
extern "C" void kernel_launch(void* const* d_in, const int* in_sizes, int n_in,
                              void* d_out, int out_size, void* d_ws, size_t ws_size,
                              hipStream_t stream) {
  const float* x = (const float*)d_in[0];
  const float* w_qkv = (const float*)d_in[1];
  const float* w_proj = (const float*)d_in[2];
  float* out = (float*)d_out;

  char* ws = (char*)d_ws;
  __bf16* xb   = (__bf16*)(ws);
  __bf16* wqb  = (__bf16*)(ws + 16777216);
  __bf16* wpb  = (__bf16*)(ws + 23068672);
  __bf16* qkvb = (__bf16*)(ws + 25165824);
  __bf16* vtb  = (__bf16*)(ws + 75497472);
  __bf16* yb   = (__bf16*)(ws + 92274688);

  // allow 72KB dynamic LDS for gemmdp (idempotent; safe under graph capture)
  hipFuncSetAttribute((const void*)gemmdp<0>, hipFuncAttributeMaxDynamicSharedMemorySize, 73728);
  hipFuncSetAttribute((const void*)gemmdp<1>, hipFuncAttributeMaxDynamicSharedMemorySize, 73728);

  cvt_all<<<1024, 256, 0, stream>>>(x, w_qkv, w_proj, xb, wqb, wpb);
  gemmdp<0><<<(NROW / 128) * (NQKV / 256), 256, 73728, stream>>>(xb, wqb, qkvb, NROW, NQKV, DM);
  vtrans<<<BATCH * NH * (TSEQ / 64), 256, 0, stream>>>(qkvb, vtb);
  attn4<<<BATCH * NH * (TSEQ / 128), 256, 0, stream>>>(qkvb, vtb, yb);
  gemmdp<1><<<(NROW / 128) * (DM / 256), 256, 73728, stream>>>(yb, wpb, out, NROW, DM, DM);
}

// Round 10
// 245.462 us; speedup vs baseline: 1.1750x; 1.0078x over previous
//
#include <hip/hip_runtime.h>
#include <hip/hip_bf16.h>
#include <stdint.h>

#define DM   1024
#define NH   16
#define DH   64
#define TSEQ 2048
#define BATCH 4
#define NROW 8192      // B*T
#define NQKV 3072

typedef __attribute__((ext_vector_type(8)))  __bf16 bf16x8;
typedef __attribute__((ext_vector_type(4)))  float  f32x4;
typedef __attribute__((ext_vector_type(16))) float  f32x16;

static __device__ __forceinline__ void gload_lds16(const __bf16* g, __bf16* l) {
  __builtin_amdgcn_global_load_lds((const __attribute__((address_space(1))) void*)g,
                                   (__attribute__((address_space(3))) void*)l, 16, 0, 0);
}
static __device__ __forceinline__ float exp2a(float x) {
  float r; asm("v_exp_f32 %0, %1" : "=v"(r) : "v"(x)); return r;
}
static __device__ __forceinline__ uint32_t cvtpk(float a, float b) {
  uint32_t r; asm("v_cvt_pk_bf16_f32 %0, %1, %2" : "=v"(r) : "v"(a), "v"(b)); return r;
}

// ---------------- fp32 -> bf16 convert: x, w_qkv (Q-rows pre-scaled), w_proj ----------------
__global__ __launch_bounds__(256) void cvt_all(const float* __restrict__ x,
                                               const float* __restrict__ wq,
                                               const float* __restrict__ wp,
                                               __bf16* __restrict__ xb,
                                               __bf16* __restrict__ wqb,
                                               __bf16* __restrict__ wpb) {
  const int n8x = NROW * DM / 8, n8q = NQKV * DM / 8, n8p = DM * DM / 8;
  const int total = n8x + n8q + n8p;
  int i = blockIdx.x * blockDim.x + threadIdx.x;
  int stride = gridDim.x * blockDim.x;
  for (; i < total; i += stride) {
    const float* src; __bf16* dst; int k;
    float sc = 1.0f;
    if (i < n8x) { src = x; dst = xb; k = i; }
    else if (i < n8x + n8q) {
      src = wq; dst = wqb; k = i - n8x;
      if (k < n8q / 3) sc = 0.125f * 1.44269504f;  // Q out-features -> log2 domain
    } else { src = wp; dst = wpb; k = i - n8x - n8q; }
    const float4* p = (const float4*)(src + (size_t)k * 8);
    float4 a = p[0], b = p[1];
    bf16x8 o;
    o[0] = (__bf16)(a.x * sc); o[1] = (__bf16)(a.y * sc);
    o[2] = (__bf16)(a.z * sc); o[3] = (__bf16)(a.w * sc);
    o[4] = (__bf16)(b.x * sc); o[5] = (__bf16)(b.y * sc);
    o[6] = (__bf16)(b.z * sc); o[7] = (__bf16)(b.w * sc);
    *(bf16x8*)(dst + (size_t)k * 8) = o;
  }
}

// ======== deep-pipeline 128x256 GEMM, C = A[M,K]*B[N,K]^T (R9 measured-good) ========
template <int OUTF32>
__global__ __launch_bounds__(256, 2) void gemmdp(const __bf16* __restrict__ A,
                                                 const __bf16* __restrict__ B,
                                                 void* __restrict__ C,
                                                 int M, int N, int K) {
  extern __shared__ __bf16 ring[];  // 3 slots x 12288 el (A 4096 + B 8192)
  const int nbn = N >> 8;
  const int nwg = gridDim.x;
  int bid = blockIdx.x;
  bid = (bid & 7) * (nwg >> 3) + (bid >> 3);  // XCD-aware swizzle (nwg % 8 == 0)
  const int bm = bid / nbn, bn = bid % nbn;
  const int tid = threadIdx.x, lane = tid & 63;
  const int wc = tid >> 6;
  const int nk = K >> 5;

  f32x4 acc[8][4];
#pragma unroll
  for (int m = 0; m < 8; m++)
#pragma unroll
    for (int n = 0; n < 4; n++) acc[m][n] = (f32x4){0.f, 0.f, 0.f, 0.f};

  const __bf16* Ab = A + (size_t)(bm * 128) * K;
  const __bf16* Bb = B + (size_t)(bn * 256) * K;

#define DP_STAGE(kt)                                                            \
  {                                                                             \
    __bf16* s_ = ring + ((kt) % 3) * 12288;                                     \
    const int k0_ = (kt) << 5;                                                  \
    _Pragma("unroll")                                                           \
    for (int it_ = 0; it_ < 2; ++it_) { /* A: 128 rows x 4 chunks */            \
      int c_ = it_ * 256 + tid;                                                 \
      int row_ = c_ >> 2, ch_ = c_ & 3;                                         \
      int srow_ = row_ ^ ((row_ >> 3) & 1);                                     \
      int scol_ = (ch_ ^ ((row_ >> 1) & 3)) * 8;                                \
      gload_lds16(Ab + (size_t)srow_ * K + k0_ + scol_, s_ + c_ * 8);           \
    }                                                                           \
    _Pragma("unroll")                                                           \
    for (int it_ = 0; it_ < 4; ++it_) { /* B: 256 rows x 4 chunks */            \
      int c_ = it_ * 256 + tid;                                                 \
      int row_ = c_ >> 2, ch_ = c_ & 3;                                         \
      int srow_ = row_ ^ ((row_ >> 3) & 1);                                     \
      int scol_ = (ch_ ^ ((row_ >> 1) & 3)) * 8;                                \
      gload_lds16(Bb + (size_t)srow_ * K + k0_ + scol_, s_ + 4096 + c_ * 8);    \
    }                                                                           \
  }

  DP_STAGE(0)
  DP_STAGE(1)

  for (int t = 0; t < nk; ++t) {
    if (t + 2 < nk) DP_STAGE(t + 2)
    if (t < nk - 2)       asm volatile("s_waitcnt vmcnt(12)" ::: "memory");
    else if (t == nk - 2) asm volatile("s_waitcnt vmcnt(6)"  ::: "memory");
    else                  asm volatile("s_waitcnt vmcnt(0)"  ::: "memory");
    __builtin_amdgcn_s_barrier();

    const __bf16* sA = ring + (t % 3) * 12288;
    const __bf16* sB = sA + 4096;
    const int cb = (lane >> 4) * 16;
    bf16x8 af[8], bfr[4];
#pragma unroll
    for (int m = 0; m < 8; m++) {
      int l = (m * 16 + (lane & 15)) * 64 + cb;
      af[m] = *(const bf16x8*)((const char*)sA + (l ^ (((l >> 7) & 7) << 4)));
    }
#pragma unroll
    for (int n = 0; n < 4; n++) {
      int l = (wc * 64 + n * 16 + (lane & 15)) * 64 + cb;
      bfr[n] = *(const bf16x8*)((const char*)sB + (l ^ (((l >> 7) & 7) << 4)));
    }
    asm volatile("s_waitcnt lgkmcnt(0)" ::: "memory");
    __builtin_amdgcn_sched_barrier(0);

    __builtin_amdgcn_s_setprio(1);
#pragma unroll
    for (int m = 0; m < 8; m++)
#pragma unroll
      for (int n = 0; n < 4; n++)
        acc[m][n] = __builtin_amdgcn_mfma_f32_16x16x32_bf16(af[m], bfr[n], acc[m][n], 0, 0, 0);
    __builtin_amdgcn_s_setprio(0);
    __builtin_amdgcn_s_barrier();
  }

  const int crow0 = bm * 128, ccol0 = bn * 256 + wc * 64;
#pragma unroll
  for (int m = 0; m < 8; m++)
#pragma unroll
    for (int n = 0; n < 4; n++) {
      int col = ccol0 + n * 16 + (lane & 15);
#pragma unroll
      for (int r = 0; r < 4; r++) {
        int row = crow0 + m * 16 + (lane >> 4) * 4 + r;
        if (OUTF32) ((float*)C)[(size_t)row * N + col] = acc[m][n][r];
        else        ((__bf16*)C)[(size_t)row * N + col] = (__bf16)acc[m][n][r];
      }
    }
}

// ---------------- V transpose: qkv V-part [b][t][h*64+d] -> vt [b][h][d][t] ----------------
__global__ __launch_bounds__(256) void vtrans(const __bf16* __restrict__ qkv,
                                              __bf16* __restrict__ vt) {
  int tt = blockIdx.x & 31;
  int h = (blockIdx.x >> 5) & 15;
  int b = blockIdx.x >> 9;
  __shared__ __bf16 tile[64 * 64];  // [t][d]
  int tid = threadIdx.x;
  int trow = tid >> 2, c16 = (tid & 3) * 16;
#pragma unroll
  for (int u = 0; u < 2; ++u)
    *(bf16x8*)&tile[trow * 64 + c16 + u * 8] =
        *(const bf16x8*)(qkv + (size_t)(b * TSEQ + tt * 64 + trow) * NQKV + 2 * DM + h * DH + c16 + u * 8);
  __syncthreads();
  int drow = tid >> 2, t16 = (tid & 3) * 16;
  bf16x8 o0, o1;
#pragma unroll
  for (int u = 0; u < 8; u++) o0[u] = tile[(t16 + u) * 64 + drow];
#pragma unroll
  for (int u = 0; u < 8; u++) o1[u] = tile[(t16 + 8 + u) * 64 + drow];
  __bf16* dst = vt + ((size_t)((b * NH + h) * DH) + drow) * TSEQ + tt * 64 + t16;
  *(bf16x8*)dst = o0;
  *(bf16x8*)(dst + 8) = o1;
}

// ---------------- causal flash attention, double-buffered prefetch (T3/T14) ----------------
// grid 1024 heavy-first; 4 waves x 32 q-rows; KV tile 128, K/V LDS double-buffered (64KB,
// 2 blocks/CU). Per tile: issue STAGE(t+1) -> compute(t) -> __syncthreads (vmcnt drain lands
// after ~1000cy of compute -> HBM latency hidden). V swizzle widened to row&15 (16 slots,
// 256B rows) to kill the 4-way b64 bank conflict; K stays row&7 (128B rows, maximal).
__global__ __launch_bounds__(256, 2) void attn5(const __bf16* __restrict__ qkv,
                                                const __bf16* __restrict__ vt,
                                                __bf16* __restrict__ y) {
  const int bid = blockIdx.x;
  const int qt = 15 - (bid >> 6);
  const int bh = bid & 63;
  const int b = bh >> 4, h = bh & 15;
  const int tid = threadIdx.x, lane = tid & 63, w = tid >> 6;
  const int lq = lane & 31, hi = lane >> 5;
  const int qb0 = qt * 128 + w * 32;

  __shared__ __bf16 Ks[2][128 * 64];  // [s][d], XOR-swizzled (row&7)
  __shared__ __bf16 Vs[2][64 * 128];  // [d][s], XOR-swizzled (row&15)

  const __bf16* qp = qkv + (size_t)(b * TSEQ + qb0 + lq) * NQKV + h * DH;
  bf16x8 qf[4];
#pragma unroll
  for (int ks = 0; ks < 4; ks++) qf[ks] = *(const bf16x8*)(qp + ks * 16 + hi * 8);

  f32x16 o0 = {}, o1 = {};
  float m = -1e30f, lsum = 0.f;

  const __bf16* kg = qkv + (size_t)b * TSEQ * NQKV + DM + h * DH;
  const __bf16* vg = vt + (size_t)((b * NH + h) * DH) * TSEQ;

#define ATTN_STAGE(bb, tt)                                                      \
  {                                                                             \
    const int s0_ = (tt) * 128;                                                 \
    _Pragma("unroll")                                                           \
    for (int it = 0; it < 4; ++it) { /* K: 128 rows x 64 */                     \
      int e = it * 256 + tid;                                                   \
      int row = e >> 3, slot = e & 7;                                           \
      int gc = (slot ^ (row & 7)) * 8;                                          \
      gload_lds16(kg + (size_t)(s0_ + row) * NQKV + gc, &Ks[bb][e * 8]);        \
    }                                                                           \
    _Pragma("unroll")                                                           \
    for (int it = 0; it < 4; ++it) { /* V: 64 rows x 128 */                     \
      int e = it * 256 + tid;                                                   \
      int row = e >> 4, slot = e & 15;                                          \
      int gc = (slot ^ (row & 15)) * 8;                                         \
      gload_lds16(vg + (size_t)row * TSEQ + s0_ + gc, &Vs[bb][e * 8]);          \
    }                                                                           \
  }

  const int nkv = qt + 1;
  ATTN_STAGE(0, 0)
  __syncthreads();

  for (int t0 = 0; t0 < nkv; ++t0) {
    const int cur = t0 & 1;
    if (t0 + 1 < nkv) ATTN_STAGE(cur ^ 1, t0 + 1)
    const int s0 = t0 * 128;

#pragma unroll
    for (int g = 0; g < 4; ++g) {
      const int s0g = s0 + g * 32;
      if (s0g <= qb0 + 31) {
        f32x16 sacc = {};
        __builtin_amdgcn_s_setprio(1);
#pragma unroll
        for (int ks = 0; ks < 4; ks++) {
          int row = g * 32 + lq;
          int cbk = (ks * 32 + hi * 16) ^ ((row & 7) << 4);
          bf16x8 kf = *(const bf16x8*)((const char*)Ks[cur] + row * 128 + cbk);
          sacc = __builtin_amdgcn_mfma_f32_32x32x16_bf16(kf, qf[ks], sacc, 0, 0, 0);
        }
        __builtin_amdgcn_s_setprio(0);
        const int qg = qb0 + lq;
        const int kvb = s0g + (hi << 2);
        if (s0g + 31 > qb0) {
#pragma unroll
          for (int r = 0; r < 16; r++) {
            const int off = (r & 3) + 8 * (r >> 2);
            if (kvb + off > qg) sacc[r] = -3.0e38f;
          }
        }
        float pm = -3.0e38f;
#pragma unroll
        for (int r = 0; r < 16; r++) pm = fmaxf(pm, sacc[r]);
        pm = fmaxf(pm, __shfl_xor(pm, 32));
        if (__any(pm > m + 8.0f)) {
          float mn = fmaxf(m, pm);
          float al = exp2a(m - mn);
          m = mn;
          lsum *= al;
#pragma unroll
          for (int r = 0; r < 16; r++) {
            const int off = (r & 3) + 8 * (r >> 2);
            float ar = __shfl(al, off + (hi << 2), 64);
            o0[r] *= ar; o1[r] *= ar;
          }
        }
        union { uint32_t u[4]; bf16x8 v; } pa0, pa1;
        {
          float pe[16];
#pragma unroll
          for (int r = 0; r < 16; r++) { pe[r] = exp2a(sacc[r] - m); lsum += pe[r]; }
#pragma unroll
          for (int i = 0; i < 4; i++) pa0.u[i] = cvtpk(pe[2 * i], pe[2 * i + 1]);
#pragma unroll
          for (int i = 0; i < 4; i++) pa1.u[i] = cvtpk(pe[8 + 2 * i], pe[9 + 2 * i]);
        }
        __builtin_amdgcn_s_setprio(1);
#pragma unroll
        for (int ks2 = 0; ks2 < 2; ks2++) {
          const bf16x8 pa = ks2 ? pa1.v : pa0.v;
#pragma unroll
          for (int dh = 0; dh < 2; dh++) {
            int row = dh * 32 + lq;
            int sw = (row & 15) << 4;
            int b0 = g * 64 + ks2 * 32 + hi * 8;
            const char* base = (const char*)Vs[cur] + row * 256;
            union { uint32_t u[4]; bf16x8 v; } vf;
            *(uint2*)&vf.u[0] = *(const uint2*)(base + (b0 ^ sw));
            *(uint2*)&vf.u[2] = *(const uint2*)(base + ((b0 + 16) ^ sw));
            if (dh == 0) o0 = __builtin_amdgcn_mfma_f32_32x32x16_bf16(pa, vf.v, o0, 0, 0, 0);
            else         o1 = __builtin_amdgcn_mfma_f32_32x32x16_bf16(pa, vf.v, o1, 0, 0, 0);
          }
        }
        __builtin_amdgcn_s_setprio(0);
      }
    }
    __syncthreads();  // drains prefetch vmcnt (overlapped with compute above) + seals cur
  }

  float Lf = lsum + __shfl_xor(lsum, 32);
  float inv = 1.0f / Lf;
#pragma unroll
  for (int r = 0; r < 16; r++) {
    const int off = (r & 3) + 8 * (r >> 2);
    float ivr = __shfl(inv, off + (hi << 2), 64);
    int qrow = qb0 + off + (hi << 2);
    __bf16* yp = y + (size_t)(b * TSEQ + qrow) * DM + h * DH;
    yp[lq] = (__bf16)(o0[r] * ivr);
    yp[32 + lq] = (__bf16)(o1[r] * ivr);
  }
}

// ---------------- launcher ----------------
extern "C" void kernel_launch(void* const* d_in, const int* in_sizes, int n_in,
                              void* d_out, int out_size, void* d_ws, size_t ws_size,
                              hipStream_t stream) {
  const float* x = (const float*)d_in[0];
  const float* w_qkv = (const float*)d_in[1];
  const float* w_proj = (const float*)d_in[2];
  float* out = (float*)d_out;

  char* ws = (char*)d_ws;
  __bf16* xb   = (__bf16*)(ws);
  __bf16* wqb  = (__bf16*)(ws + 16777216);
  __bf16* wpb  = (__bf16*)(ws + 23068672);
  __bf16* qkvb = (__bf16*)(ws + 25165824);
  __bf16* vtb  = (__bf16*)(ws + 75497472);
  __bf16* yb   = (__bf16*)(ws + 92274688);

  hipFuncSetAttribute((const void*)gemmdp<0>, hipFuncAttributeMaxDynamicSharedMemorySize, 73728);
  hipFuncSetAttribute((const void*)gemmdp<1>, hipFuncAttributeMaxDynamicSharedMemorySize, 73728);

  cvt_all<<<1024, 256, 0, stream>>>(x, w_qkv, w_proj, xb, wqb, wpb);
  gemmdp<0><<<(NROW / 128) * (NQKV / 256), 256, 73728, stream>>>(xb, wqb, qkvb, NROW, NQKV, DM);
  vtrans<<<BATCH * NH * (TSEQ / 64), 256, 0, stream>>>(qkvb, vtb);
  attn5<<<BATCH * NH * (TSEQ / 128), 256, 0, stream>>>(qkvb, vtb, yb);
  gemmdp<1><<<(NROW / 128) * (DM / 256), 256, 73728, stream>>>(yb, wpb, out, NROW, DM, DM);
}